// Round 5
// baseline (697.735 us; speedup 1.0000x reference)
//
#include <hip/hip_runtime.h>

#define B_ 4
#define S_ 2048
#define H_ 1024
#define NH_ 16
#define HD_ 64
#define FF_ 4096

typedef __attribute__((ext_vector_type(8))) short bfx8;
typedef __attribute__((ext_vector_type(4))) float f32x4;
typedef __attribute__((ext_vector_type(16))) float f32x16;
typedef __attribute__((ext_vector_type(4))) unsigned short us4;

__device__ __forceinline__ unsigned short f2bf(float x) {
  union { float f; unsigned u; } c; c.f = x;
  unsigned r = c.u + 0x7FFFu + ((c.u >> 16) & 1u);
  return (unsigned short)(r >> 16);
}
__device__ __forceinline__ unsigned cvtpk(float a, float b) {
  unsigned r;
  asm("v_cvt_pk_bf16_f32 %0, %1, %2" : "=v"(r) : "v"(a), "v"(b));
  return r;
}
__device__ __forceinline__ f32x4 mfma16(bfx8 a, bfx8 b, f32x4 c) {
  return __builtin_amdgcn_mfma_f32_16x16x32_bf16(a, b, c, 0, 0, 0);
}
__device__ __forceinline__ f32x16 mfma32(bfx8 a, bfx8 b, f32x16 c) {
  return __builtin_amdgcn_mfma_f32_32x32x16_bf16(a, b, c, 0, 0, 0);
}
__device__ __forceinline__ void async16(const unsigned short* g, unsigned short* l) {
  __builtin_amdgcn_global_load_lds(
      (const __attribute__((address_space(1))) unsigned int*)g,
      (__attribute__((address_space(3))) unsigned int*)l, 16, 0, 0);
}
__device__ __forceinline__ float gelu_f(float x) {
  float u = 0.7978845608028654f * (x + 0.044715f * x * x * x);
  float e = __expf(2.f * u);
  float t = 1.f - 2.f / (e + 1.f);
  return 0.5f * x * (1.f + t);
}

// ---------------- fp32 -> bf16 convert ----------------
__global__ __launch_bounds__(256) void k_cvt(const float* __restrict__ in,
                                             unsigned short* __restrict__ out, int n4) {
  int i = blockIdx.x * 256 + threadIdx.x;
  if (i >= n4) return;
  float4 v = ((const float4*)in)[i];
  us4 o; o.x = f2bf(v.x); o.y = f2bf(v.y); o.z = f2bf(v.z); o.w = f2bf(v.w);
  ((us4*)out)[i] = o;
}

// ---------------- concat 3 bias vectors ----------------
__global__ __launch_bounds__(256) void k_cat3(const float* __restrict__ a,
                                              const float* __restrict__ b,
                                              const float* __restrict__ c,
                                              float* __restrict__ o) {
  int i = blockIdx.x * 256 + threadIdx.x;
  if (i >= 3 * H_) return;
  o[i] = i < H_ ? a[i] : (i < 2 * H_ ? b[i - H_] : c[i - 2 * H_]);
}

// ---------------- W [K][N] f32 -> WT [N][K] bf16 ----------------
__global__ __launch_bounds__(256) void k_wtrans(const float* __restrict__ W,
                                                unsigned short* __restrict__ WT,
                                                int K, int N) {
  __shared__ float tile[64][65];
  int k0 = blockIdx.x * 64, n0 = blockIdx.y * 64;
  int t = threadIdx.x;
#pragma unroll
  for (int i = 0; i < 16; i++) {
    int li = t + i * 256;
    int kl = li >> 6, nl = li & 63;
    tile[kl][nl] = W[(size_t)(k0 + kl) * N + n0 + nl];
  }
  __syncthreads();
#pragma unroll
  for (int i = 0; i < 16; i++) {
    int li = t + i * 256;
    int nl = li >> 6, kl = li & 63;
    WT[(size_t)(n0 + nl) * K + k0 + kl] = f2bf(tile[kl][nl]);
  }
}

// ------------- V view [B*S][ld] bf16 -> VT [B*NH][HD][S] bf16 -------------
__global__ __launch_bounds__(256) void k_vtrans(const unsigned short* __restrict__ v,
                                                int ld, unsigned short* __restrict__ vt) {
  __shared__ unsigned short tile[64][65];
  int s0 = blockIdx.x * 64;
  int bh = blockIdx.y;
  int b = bh >> 4, h = bh & 15;
  int t = threadIdx.x;
#pragma unroll
  for (int i = 0; i < 16; i++) {
    int li = t + i * 256;
    int sl = li >> 6, dl = li & 63;
    tile[sl][dl] = v[(size_t)(b * S_ + s0 + sl) * ld + h * HD_ + dl];
  }
  __syncthreads();
#pragma unroll
  for (int i = 0; i < 16; i++) {
    int li = t + i * 256;
    int dl = li >> 6, sl = li & 63;
    vt[((size_t)bh * HD_ + dl) * S_ + s0 + sl] = tile[sl][dl];
  }
}

// ============ deep-pipelined GEMM: C = A[M][K] @ BT[N][K]^T + bias ============
// BM=256, BK=32, 512 threads = 8 waves (WM x WN). Two LDS buffers; tile T(t+2)
// staged (global_load_lds) right after __syncthreads frees buf[t&1]; loads stay
// in flight across the raw s_barrier and a full MFMA iteration before the next
// __syncthreads drains them -> latency covered, no per-step vmcnt(0) stall.
// EPI: 0 = bf16 out, 2 = f32 out, 3 = bf16 gelu
template <int BN, int WM, int EPI>
__global__ __launch_bounds__(512, 2) void k_gemm256(
    const unsigned short* __restrict__ A, const unsigned short* __restrict__ BT,
    const float* __restrict__ bias, float* __restrict__ Cf,
    unsigned short* __restrict__ Cb, int M, int N, int K, int nbx) {
  constexpr int WN = 8 / WM;
  constexpr int MR = 256 / WM / 16;  // A fragments per wave
  constexpr int NR = BN / WN / 16;   // B fragments per wave
  constexpr int NB = BN / 128;       // B-tile loads per thread
  __shared__ unsigned short smA[2][256 * 32];
  __shared__ unsigned short smB[2][BN * 32];

  const int nwg = gridDim.x;
  const int o = blockIdx.x;
  const int swz = (o & 7) * (nwg >> 3) + (o >> 3);  // XCD chunk (nwg % 8 == 0)
  const int bx = swz % nbx, by = swz / nbx;

  const int tid = threadIdx.x, lane = tid & 63, wid = tid >> 6;
  const int wm = wid & (WM - 1), wn = wid / WM;
  const int lrow = lane & 15, lk = lane >> 4;
  const int rowM = by * 256, rowN = bx * BN;
  const int srow = tid >> 2, scol = (tid & 3) * 8;
  const unsigned short* gA = A + (size_t)(rowM + srow) * K + scol;
  const unsigned short* gB = BT + (size_t)(rowN + srow) * K + scol;

  f32x4 acc[MR][NR] = {};
  const int NK = K / 32;

  // prologue: stage T0 -> buf0, T1 -> buf1
#pragma unroll
  for (int j = 0; j < 2; j++)
    async16(gA + (size_t)j * 128 * K, &smA[0][tid * 8 + j * 4096]);
#pragma unroll
  for (int j = 0; j < NB; j++)
    async16(gB + (size_t)j * 128 * K, &smB[0][tid * 8 + j * 4096]);
#pragma unroll
  for (int j = 0; j < 2; j++)
    async16(gA + 32 + (size_t)j * 128 * K, &smA[1][tid * 8 + j * 4096]);
#pragma unroll
  for (int j = 0; j < NB; j++)
    async16(gB + 32 + (size_t)j * 128 * K, &smB[1][tid * 8 + j * 4096]);
  __syncthreads();  // drains all; T0+T1 resident

  for (int t = 0; t < NK; t++) {
    const unsigned short* LA = smA[t & 1];
    const unsigned short* LB = smB[t & 1];
    bfx8 af[MR], bf[NR];
#pragma unroll
    for (int m = 0; m < MR; m++)
      af[m] = *(const bfx8*)&LA[(wm * (MR * 16) + m * 16 + lrow) * 32 + lk * 8];
#pragma unroll
    for (int n = 0; n < NR; n++)
      bf[n] = *(const bfx8*)&LB[(wn * (NR * 16) + n * 16 + lrow) * 32 + lk * 8];
    __builtin_amdgcn_s_setprio(1);
#pragma unroll
    for (int m = 0; m < MR; m++)
#pragma unroll
      for (int n = 0; n < NR; n++)
        acc[m][n] = mfma16(af[m], bf[n], acc[m][n]);
    __builtin_amdgcn_s_setprio(0);

    // #1: all waves done reading buf[t&1]; also drains T(t+1)'s old loads (free)
    __syncthreads();

    if (t + 2 < NK) {  // stage T(t+2) into the buffer just freed
      const int k0 = (t + 2) * 32;
      unsigned short* dA = &smA[t & 1][tid * 8];
      unsigned short* dB = &smB[t & 1][tid * 8];
#pragma unroll
      for (int j = 0; j < 2; j++)
        async16(gA + k0 + (size_t)j * 128 * K, dA + j * 4096);
#pragma unroll
      for (int j = 0; j < NB; j++)
        async16(gB + k0 + (size_t)j * 128 * K, dB + j * 4096);
    }
    // #2: raw barrier -- staged loads stay in flight across it
    __builtin_amdgcn_s_barrier();
    __builtin_amdgcn_sched_barrier(0);
  }

#pragma unroll
  for (int n = 0; n < NR; n++) {
    const int gcol = rowN + wn * (NR * 16) + n * 16 + lrow;
    const float bz = bias[gcol];
#pragma unroll
    for (int m = 0; m < MR; m++) {
      const int grow = rowM + wm * (MR * 16) + m * 16 + lk * 4;
#pragma unroll
      for (int r = 0; r < 4; r++) {
        float v = acc[m][n][r] + bz;
        if (EPI == 3) v = gelu_f(v);
        size_t idx = (size_t)(grow + r) * N + gcol;
        if (EPI == 2) Cf[idx] = v;
        else Cb[idx] = f2bf(v);
      }
    }
  }
}

// ------- fused flash attention, 32x32 MFMA, LDS-staged fragment tiles -------
__global__ __launch_bounds__(256) void k_attn(
    const unsigned short* __restrict__ qkv, const unsigned short* __restrict__ vt,
    const float* __restrict__ mask, unsigned short* __restrict__ ctx) {
  __shared__ unsigned short lds[2][8192];
  const int id = blockIdx.x;
  const int jj = (id & 7) * 128 + (id >> 3);  // XCD-chunk: 8 heads per XCD
  const int bh = jj >> 4, qb = jj & 15;
  const int b = bh >> 4, h = bh & 15;
  const int tid = threadIdx.x, wid = tid >> 6, lane = tid & 63;
  const int lq = lane & 31, hi = lane >> 5;
  const int q0 = qb * 128 + wid * 32;
  const int LD = 3 * H_;
  const int NT = S_ / 64;

  const size_t KC = ((size_t)b * S_ + (tid & 31)) * LD + H_ + h * HD_ +
                    (tid >> 6) * 16 + ((tid >> 5) & 1) * 8;
  const size_t VC = ((size_t)bh * HD_ + ((tid >> 6) & 1) * 32 + (tid & 31)) * S_ +
                    (tid >> 7) * 16 + ((tid >> 5) & 1) * 8;

  const size_t qrow = ((size_t)b * S_ + q0 + lq) * LD + h * HD_;
  bfx8 qf[4];
#pragma unroll
  for (int c = 0; c < 4; c++) qf[c] = *(const bfx8*)&qkv[qrow + c * 16 + hi * 8];

  {
    unsigned short* lb = &lds[0][wid * 512];
    async16(qkv + KC, lb);
    async16(qkv + KC + (size_t)32 * LD, lb + 2048);
    async16(vt + VC, lb + 4096);
    async16(vt + VC + 32, lb + 6144);
  }
  asm volatile("s_waitcnt vmcnt(0)" ::: "memory");
  __syncthreads();

  float m_run = -1e30f, l_run = 0.f;
  f32x16 o0 = {}, o1 = {};
  const float* mrow = mask + (size_t)b * S_;

  for (int t = 0; t < NT; t++) {
    const int bb = t & 1;
    if (t + 1 < NT) {
      unsigned short* lb = &lds[bb ^ 1][wid * 512];
      const size_t ko = KC + (size_t)((t + 1) * 64) * LD;
      const size_t vo = VC + (size_t)(t + 1) * 64;
      async16(qkv + ko, lb);
      async16(qkv + ko + (size_t)32 * LD, lb + 2048);
      async16(vt + vo, lb + 4096);
      async16(vt + vo + 32, lb + 6144);
    }
    const unsigned short* L = lds[bb];

    bfx8 kf0[4], kf1[4];
#pragma unroll
    for (int c = 0; c < 4; c++) {
      kf0[c] = *(const bfx8*)&L[(c * 64 + lane) * 8];
      kf1[c] = *(const bfx8*)&L[((4 + c) * 64 + lane) * 8];
    }
    f32x16 s0 = {}, s1 = {};
    __builtin_amdgcn_s_setprio(1);
#pragma unroll
    for (int c = 0; c < 4; c++) s0 = mfma32(kf0[c], qf[c], s0);
#pragma unroll
    for (int c = 0; c < 4; c++) s1 = mfma32(kf1[c], qf[c], s1);
    __builtin_amdgcn_s_setprio(0);

    const int kb = t * 64;
#pragma unroll
    for (int g = 0; g < 4; g++) {
      const f32x4 m0 = *(const f32x4*)&mrow[kb + g * 8 + hi * 4];
      const f32x4 m1 = *(const f32x4*)&mrow[kb + 32 + g * 8 + hi * 4];
#pragma unroll
      for (int i = 0; i < 4; i++) {
        s0[g * 4 + i] = s0[g * 4 + i] * 0.125f + m0[i];
        s1[g * 4 + i] = s1[g * 4 + i] * 0.125f + m1[i];
      }
    }
    float mx = s0[0];
#pragma unroll
    for (int r = 1; r < 16; r++) mx = fmaxf(mx, s0[r]);
#pragma unroll
    for (int r = 0; r < 16; r++) mx = fmaxf(mx, s1[r]);
    mx = fmaxf(mx, __shfl_xor(mx, 32));
    if (!__all(mx <= m_run + 8.f)) {
      const float m_new = fmaxf(m_run, mx);
      const float scale = __expf(m_run - m_new);
      l_run *= scale;
#pragma unroll
      for (int r = 0; r < 16; r++) { o0[r] *= scale; o1[r] *= scale; }
      m_run = m_new;
    }
    float ps = 0.f;
#pragma unroll
    for (int r = 0; r < 16; r++) { s0[r] = __expf(s0[r] - m_run); ps += s0[r]; }
#pragma unroll
    for (int r = 0; r < 16; r++) { s1[r] = __expf(s1[r] - m_run); ps += s1[r]; }
    ps += __shfl_xor(ps, 32);
    l_run += ps;

    unsigned t0A0 = cvtpk(s0[0], s0[1]), t0A1 = cvtpk(s0[2], s0[3]);
    unsigned t0B0 = cvtpk(s0[4], s0[5]), t0B1 = cvtpk(s0[6], s0[7]);
    unsigned t0C0 = cvtpk(s0[8], s0[9]), t0C1 = cvtpk(s0[10], s0[11]);
    unsigned t0D0 = cvtpk(s0[12], s0[13]), t0D1 = cvtpk(s0[14], s0[15]);
    unsigned t1A0 = cvtpk(s1[0], s1[1]), t1A1 = cvtpk(s1[2], s1[3]);
    unsigned t1B0 = cvtpk(s1[4], s1[5]), t1B1 = cvtpk(s1[6], s1[7]);
    unsigned t1C0 = cvtpk(s1[8], s1[9]), t1C1 = cvtpk(s1[10], s1[11]);
    unsigned t1D0 = cvtpk(s1[12], s1[13]), t1D1 = cvtpk(s1[14], s1[15]);
    unsigned x0 = __shfl_xor(hi ? t0A0 : t0B0, 32);
    unsigned x1 = __shfl_xor(hi ? t0A1 : t0B1, 32);
    unsigned x2 = __shfl_xor(hi ? t0C0 : t0D0, 32);
    unsigned x3 = __shfl_xor(hi ? t0C1 : t0D1, 32);
    unsigned x4 = __shfl_xor(hi ? t1A0 : t1B0, 32);
    unsigned x5 = __shfl_xor(hi ? t1A1 : t1B1, 32);
    unsigned x6 = __shfl_xor(hi ? t1C0 : t1D0, 32);
    unsigned x7 = __shfl_xor(hi ? t1C1 : t1D1, 32);
    union { unsigned u[4]; bfx8 v; } p00, p01, p10, p11;
    p00.u[0] = hi ? x0 : t0A0;  p00.u[1] = hi ? x1 : t0A1;
    p00.u[2] = hi ? t0B0 : x0;  p00.u[3] = hi ? t0B1 : x1;
    p01.u[0] = hi ? x2 : t0C0;  p01.u[1] = hi ? x3 : t0C1;
    p01.u[2] = hi ? t0D0 : x2;  p01.u[3] = hi ? t0D1 : x3;
    p10.u[0] = hi ? x4 : t1A0;  p10.u[1] = hi ? x5 : t1A1;
    p10.u[2] = hi ? t1B0 : x4;  p10.u[3] = hi ? t1B1 : x5;
    p11.u[0] = hi ? x6 : t1C0;  p11.u[1] = hi ? x7 : t1C1;
    p11.u[2] = hi ? t1D0 : x6;  p11.u[3] = hi ? t1D1 : x7;

    bfx8 v00 = *(const bfx8*)&L[4096 + (0 * 64 + lane) * 8];
    bfx8 v10 = *(const bfx8*)&L[4096 + (1 * 64 + lane) * 8];
    bfx8 v01 = *(const bfx8*)&L[4096 + (2 * 64 + lane) * 8];
    bfx8 v11 = *(const bfx8*)&L[4096 + (3 * 64 + lane) * 8];
    bfx8 v02 = *(const bfx8*)&L[4096 + (4 * 64 + lane) * 8];
    bfx8 v12 = *(const bfx8*)&L[4096 + (5 * 64 + lane) * 8];
    bfx8 v03 = *(const bfx8*)&L[4096 + (6 * 64 + lane) * 8];
    bfx8 v13 = *(const bfx8*)&L[4096 + (7 * 64 + lane) * 8];
    __builtin_amdgcn_s_setprio(1);
    o0 = mfma32(v00, p00.v, o0);
    o0 = mfma32(v01, p01.v, o0);
    o0 = mfma32(v02, p10.v, o0);
    o0 = mfma32(v03, p11.v, o0);
    o1 = mfma32(v10, p00.v, o1);
    o1 = mfma32(v11, p01.v, o1);
    o1 = mfma32(v12, p10.v, o1);
    o1 = mfma32(v13, p11.v, o1);
    __builtin_amdgcn_s_setprio(0);

    asm volatile("s_waitcnt vmcnt(0)" ::: "memory");
    __syncthreads();
  }

  const float inv = 1.f / l_run;
  unsigned short* crow = ctx + ((size_t)b * S_ + q0 + lq) * H_ + h * HD_;
#pragma unroll
  for (int g = 0; g < 4; g++) {
    us4 w0, w1;
#pragma unroll
    for (int i = 0; i < 4; i++) {
      w0[i] = f2bf(o0[g * 4 + i] * inv);
      w1[i] = f2bf(o1[g * 4 + i] * inv);
    }
    *(us4*)&crow[g * 8 + hi * 4] = w0;
    *(us4*)&crow[32 + g * 8 + hi * 4] = w1;
  }
}

// ---------------- residual + layernorm ----------------
template <int WB>
__global__ __launch_bounds__(256) void k_ln(
    const float* __restrict__ xa, const float* __restrict__ xb,
    const float* __restrict__ g, const float* __restrict__ bt,
    float* __restrict__ outf, unsigned short* __restrict__ outb) {
  const int row = blockIdx.x;
  const int t = threadIdx.x;
  const size_t off = (size_t)row * H_ + t * 4;
  float4 va = *(const float4*)(xa + off);
  float4 vb = *(const float4*)(xb + off);
  float v0 = va.x + vb.x, v1 = va.y + vb.y, v2 = va.z + vb.z, v3 = va.w + vb.w;
  float s = (v0 + v1) + (v2 + v3);
#pragma unroll
  for (int d = 1; d < 64; d <<= 1) s += __shfl_xor(s, d);
  __shared__ float red1[4], red2[4];
  const int wid = t >> 6, lane = t & 63;
  if (lane == 0) red1[wid] = s;
  __syncthreads();
  const float mean = (red1[0] + red1[1] + red1[2] + red1[3]) * (1.f / H_);
  float d0 = v0 - mean, d1 = v1 - mean, d2 = v2 - mean, d3 = v3 - mean;
  float ss = (d0 * d0 + d1 * d1) + (d2 * d2 + d3 * d3);
#pragma unroll
  for (int d = 1; d < 64; d <<= 1) ss += __shfl_xor(ss, d);
  if (lane == 0) red2[wid] = ss;
  __syncthreads();
  const float var = (red2[0] + red2[1] + red2[2] + red2[3]) * (1.f / H_);
  const float rstd = rsqrtf(var + 1e-12f);
  const float4 gv = *(const float4*)(g + t * 4);
  const float4 bv = *(const float4*)(bt + t * 4);
  float y0 = d0 * rstd * gv.x + bv.x;
  float y1 = d1 * rstd * gv.y + bv.y;
  float y2 = d2 * rstd * gv.z + bv.z;
  float y3 = d3 * rstd * gv.w + bv.w;
  float4 yo; yo.x = y0; yo.y = y1; yo.z = y2; yo.w = y3;
  *(float4*)(outf + off) = yo;
  if (WB) {
    us4 ob; ob.x = f2bf(y0); ob.y = f2bf(y1); ob.z = f2bf(y2); ob.w = f2bf(y3);
    *(us4*)(outb + off) = ob;
  }
}

extern "C" void kernel_launch(void* const* d_in, const int* in_sizes, int n_in,
                              void* d_out, int out_size, void* d_ws, size_t ws_size,
                              hipStream_t stream) {
  const float* x    = (const float*)d_in[0];
  const float* mask = (const float*)d_in[1];
  const float* Wq = (const float*)d_in[2];
  const float* bq = (const float*)d_in[3];
  const float* Wk = (const float*)d_in[4];
  const float* bk = (const float*)d_in[5];
  const float* Wv = (const float*)d_in[6];
  const float* bv = (const float*)d_in[7];
  const float* Wo = (const float*)d_in[8];
  const float* bo = (const float*)d_in[9];
  const float* g1  = (const float*)d_in[10];
  const float* be1 = (const float*)d_in[11];
  const float* W1 = (const float*)d_in[12];
  const float* b1 = (const float*)d_in[13];
  const float* W2 = (const float*)d_in[14];
  const float* b2 = (const float*)d_in[15];
  const float* g2  = (const float*)d_in[16];
  const float* be2 = (const float*)d_in[17];
  float* out = (float*)d_out;

  char* ws = (char*)d_ws;
  unsigned short* WT   = (unsigned short*)(ws + 0);          // 8 MiB (W1T max)
  unsigned short* XBF  = (unsigned short*)(ws + 8388608);    // 16 MiB; later X1BF
  unsigned short* QKV  = (unsigned short*)(ws + 25165824);   // 48 MiB [8192][3072]
  unsigned short* VT   = (unsigned short*)(ws + 75497472);   // 16 MiB
  unsigned short* FFBF = (unsigned short*)(ws + 92274688);   // 64 MiB
  unsigned short* CTX  = (unsigned short*)(ws + 159383552);  // 16 MiB
  float* BIAS3 = (float*)CTX;                 // 12 KiB, dead before CTX written
  float* ATTN  = (float*)QKV;                 // 32 MiB, QKV dead after attn
  float* X1    = ATTN;                        // LN1 in-place
  unsigned short* X1BF = XBF;                 // XBF dead after QKV GEMM
  float* FF2   = (float*)(ws + 58720256);     // 32 MiB (over dead QKV tail + VT)

  // x -> bf16; bias concat
  k_cvt<<<8192, 256, 0, stream>>>(x, XBF, (B_ * S_ * H_) / 4);
  k_cat3<<<12, 256, 0, stream>>>(bq, bk, bv, BIAS3);
  // fused QKV projection: [8192][3072]
  k_wtrans<<<dim3(16, 16), 256, 0, stream>>>(Wq, WT, H_, H_);
  k_wtrans<<<dim3(16, 16), 256, 0, stream>>>(Wk, WT + (size_t)1024 * H_, H_, H_);
  k_wtrans<<<dim3(16, 16), 256, 0, stream>>>(Wv, WT + (size_t)2048 * H_, H_, H_);
  k_gemm256<256, 2, 0><<<384, 512, 0, stream>>>(XBF, WT, BIAS3, nullptr, QKV,
                                                B_ * S_, 3 * H_, H_, 12);
  // V transpose per head
  k_vtrans<<<dim3(32, 64), 256, 0, stream>>>(QKV + 2048, 3 * H_, VT);
  // fused attention -> CTX
  k_attn<<<1024, 256, 0, stream>>>(QKV, VT, mask, CTX);
  // output projection -> ATTN (f32)
  k_wtrans<<<dim3(16, 16), 256, 0, stream>>>(Wo, WT, H_, H_);
  k_gemm256<128, 4, 2><<<256, 512, 0, stream>>>(CTX, WT, bo, ATTN, nullptr,
                                                B_ * S_, H_, H_, 8);
  // LN1 (in-place over ATTN) + bf16 copy
  k_ln<1><<<8192, 256, 0, stream>>>(x, ATTN, g1, be1, X1, X1BF);
  // FF1 + gelu -> FFBF
  k_wtrans<<<dim3(16, 64), 256, 0, stream>>>(W1, WT, H_, FF_);
  k_gemm256<256, 2, 3><<<512, 512, 0, stream>>>(X1BF, WT, b1, nullptr, FFBF,
                                                B_ * S_, FF_, H_, 16);
  // FF2 -> f32
  k_wtrans<<<dim3(64, 16), 256, 0, stream>>>(W2, WT, FF_, H_);
  k_gemm256<128, 4, 2><<<256, 512, 0, stream>>>(FFBF, WT, b2, FF2, nullptr,
                                                B_ * S_, H_, FF_, 8);
  // LN2 -> out
  k_ln<0><<<8192, 256, 0, stream>>>(X1, FF2, g2, be2, out, nullptr);
}